// Round 6
// baseline (4796.211 us; speedup 1.0000x reference)
//
#include <hip/hip_runtime.h>
#include <hip/hip_bf16.h>

typedef __attribute__((ext_vector_type(8))) short short8;
typedef __attribute__((ext_vector_type(4))) float f32x4;
typedef __hip_bfloat16 bf16;

__device__ __forceinline__ short f2bs_rn(float f) {   // fast RNE-ish bf16 pack
    unsigned u = __builtin_bit_cast(unsigned, f);
    u += 0x7FFF + ((u >> 16) & 1);
    return (short)(u >> 16);
}
__device__ __forceinline__ float bs2f(short s) {
    unsigned u = ((unsigned)(unsigned short)s) << 16;
    return __builtin_bit_cast(float, u);
}
__device__ __forceinline__ float ldf(const void* p, int i, int flag) {
    return flag ? bs2f(((const short*)p)[i]) : ((const float*)p)[i];
}
__device__ __forceinline__ short ldbits(const void* p, int i, int flag) {
    return flag ? ((const short*)p)[i] : f2bs_rn(((const float*)p)[i]);
}
__device__ __forceinline__ void stf(void* p, int i, float v, int flag) {
    if (flag) ((bf16*)p)[i] = __float2bfloat16(v);
    else ((float*)p)[i] = v;
}
__device__ __forceinline__ float nz(float v) { return (v == v) ? v : 0.f; }
// rcp-based: silu(-big)->-0, sigm(-big)->0 (exact limits), no div chain
__device__ __forceinline__ float siluf(float v) {
    return v * __builtin_amdgcn_rcpf(1.f + __expf(-v));
}
__device__ __forceinline__ float sigmf(float v) {
    return __builtin_amdgcn_rcpf(1.f + __expf(-v));
}

// ---------------------------------------------------------------------------
__global__ void detect_kernel(const unsigned int* __restrict__ hw, int* __restrict__ flag) {
    unsigned int w = hw[threadIdx.x];
    unsigned int e = (w >> 7) & 0xFF;
    bool ok = (e >= 113 && e <= 135);
    unsigned long long m = __ballot(ok);
    if (threadIdx.x == 0) *flag = (__popcll(m) >= 32) ? 1 : 0;
}

// ---------------------------------------------------------------------------
// prep: transposed bf16 edge weights; fp32 bias block; TRANSPOSED bf16
// node/vel weights ([out][in] so the node kernel can short8-load rows).
// ---------------------------------------------------------------------------
__global__ void prep_kernel(
    const void* eW1, const void* eW2, const void* cW1, const void* iW1,
    const void* eb1, const void* eb2, const void* cb1, const void* cw2,
    const void* ib1, const void* iw2, const void* ib2, const void* nb1,
    const void* nb2, const void* vb1, const void* vW2,
    const void* nW1, const void* nW2, const void* vW1,
    short* __restrict__ W1t, short* __restrict__ W2t,
    short* __restrict__ cW1t, short* __restrict__ iW1t,
    float* __restrict__ biasblk, short* __restrict__ nW1T,
    short* __restrict__ nW2T, short* __restrict__ vW1T,
    const int* __restrict__ flagp) {
    const int flag = *flagp;
    int i = blockIdx.x * 256 + threadIdx.x;
    if (i < 36864) { int n = i / 288, k = i % 288; W1t[i] = (k < 258) ? ldbits(eW1, k * 128 + n, flag) : (short)0; return; }
    i -= 36864;
    if (i < 16384) { int n = i / 128, k = i % 128; W2t[i] = ldbits(eW2, k * 128 + n, flag); return; }
    i -= 16384;
    if (i < 16384) { int n = i / 128, k = i % 128; cW1t[i] = ldbits(cW1, k * 128 + n, flag); return; }
    i -= 16384;
    if (i < 8192) { int n = i / 128, k = i % 128; iW1t[i] = ldbits(iW1, k * 64 + n, flag); return; }
    i -= 8192;
    if (i < 1156) {
        float v;
        if (i < 128) v = ldf(eb1, i, flag);
        else if (i < 256) v = ldf(eb2, i - 128, flag);
        else if (i < 384) v = ldf(cb1, i - 256, flag);
        else if (i < 512) v = ldf(cw2, i - 384, flag);
        else if (i < 576) v = ldf(ib1, i - 512, flag);
        else if (i < 640) v = ldf(iw2, i - 576, flag);
        else if (i < 644) v = (i == 640) ? ldf(ib2, 0, flag) : 0.f;
        else if (i < 772) v = ldf(nb1, i - 644, flag);
        else if (i < 900) v = ldf(nb2, i - 772, flag);
        else if (i < 1028) v = ldf(vb1, i - 900, flag);
        else v = ldf(vW2, i - 1028, flag);
        biasblk[i] = v;
        return;
    }
    i -= 1156;
    if (i < 32768) { int j = i / 256, k = i % 256; nW1T[i] = ldbits(nW1, k * 128 + j, flag); return; }
    i -= 32768;
    if (i < 16384) { int j = i / 128, k = i % 128; nW2T[i] = ldbits(nW2, k * 128 + j, flag); return; }
    i -= 16384;
    if (i < 16384) { int j = i / 128, k = i % 128; vW1T[i] = ldbits(vW1, k * 128 + j, flag); }
}

// ---------------------------------------------------------------------------
__global__ void convh_kernel(const void* __restrict__ h, short* __restrict__ hb,
                             const int* __restrict__ flagp, int n) {
    const int flag = *flagp;
    int i = blockIdx.x * 256 + threadIdx.x;
    if (i < n) hb[i] = ldbits(h, i, flag);
}

__global__ void convaux_kernel(const void* __restrict__ x, const void* __restrict__ ea,
                               float* __restrict__ xf, float* __restrict__ eaf,
                               const int* __restrict__ flagp, int nx, int ne) {
    const int flag = *flagp;
    int i = blockIdx.x * 256 + threadIdx.x;
    if (i < nx) { xf[i] = ldf(x, i, flag); return; }
    i -= nx;
    if (i < ne) eaf[i] = ldf(ea, i, flag);
}

// ---------------------------------------------------------------------------
// CSR build
// ---------------------------------------------------------------------------
__global__ void count_kernel(const int* __restrict__ erow, int* __restrict__ cnt, int E) {
    int i = blockIdx.x * 256 + threadIdx.x;
    if (i < E) atomicAdd(&cnt[erow[i]], 1);
}

__global__ __launch_bounds__(1024) void scan1_kernel(const int* __restrict__ cnt,
                                                     int* __restrict__ off,
                                                     int* __restrict__ bsum, int N) {
    __shared__ int sm[1024];
    int t = threadIdx.x, i = blockIdx.x * 1024 + t;
    int c = (i < N) ? cnt[i] : 0;
    sm[t] = c;
    __syncthreads();
    for (int d = 1; d < 1024; d <<= 1) {
        int v = (t >= d) ? sm[t - d] : 0;
        __syncthreads();
        sm[t] += v;
        __syncthreads();
    }
    if (i < N) off[i] = sm[t] - c;
    if (t == 1023) bsum[blockIdx.x] = sm[1023];
}
__global__ void scan2_kernel(const int* __restrict__ bsum, int* __restrict__ bpre, int nb) {
    if (threadIdx.x == 0) {
        int run = 0;
        for (int b = 0; b < nb; ++b) { bpre[b] = run; run += bsum[b]; }
    }
}
__global__ void scan3_kernel(int* __restrict__ off, const int* __restrict__ bpre, int N) {
    int i = blockIdx.x * 256 + threadIdx.x;
    if (i < N) off[i] += bpre[i >> 10];
}
__global__ void fill_kernel(const int* __restrict__ erow, const int* __restrict__ off,
                            int* __restrict__ cur, int* __restrict__ elist, int E) {
    int i = blockIdx.x * 256 + threadIdx.x;
    if (i < E) {
        int r = erow[i];
        int p = off[r] + atomicAdd(&cur[r], 1);
        elist[p] = i;
    }
}

// ---------------------------------------------------------------------------
// edge kernel: 256 thr = 4 waves, 32 edges/wave (2 m-tiles of 16).
// GEMM1 for both m, then per-m pipeline (GEMM2 -> mbuf store -> GEMM4/eij ->
// GEMM3/phi -> xbuf). LDS: sW slice 18.4 KB + tiles[4] 17.4 KB = 35.8 KB
// -> 4 blocks/CU.  mbuf holds RAW m_ij (bf16); eij goes in xbuf[e*4+3].
// ---------------------------------------------------------------------------
__device__ __forceinline__ void stage_w(const short* __restrict__ src, int grs, int k0,
                                        int nrows, int wk, short* __restrict__ sW, int tid) {
    const int upr = wk >> 3;
    const int units = nrows * upr;
    for (int u = tid; u < units; u += 256) {
        int n = u / upr, c = u % upr;
        *(short8*)(sW + n * 72 + c * 8) = *(const short8*)(src + n * grs + k0 + c * 8);
    }
}

template <bool ATOMIC>
__global__ __launch_bounds__(256, 4) void edge_kernel(
    const short* __restrict__ hb, const float* __restrict__ xf,
    const float* __restrict__ eaf,
    const int* __restrict__ erow, const int* __restrict__ ecol,
    const short* __restrict__ W1t, const short* __restrict__ W2t,
    const short* __restrict__ cW1t, const short* __restrict__ iW1t,
    const float* __restrict__ biasblk,
    short* __restrict__ mbuf, float* __restrict__ xbuf,
    float* __restrict__ m_i, float* __restrict__ agg_x, int E) {
    __shared__ __align__(16) short sW[128 * 72];        // 18432 B
    __shared__ __align__(16) short tiles[4][16 * 136];  // 17408 B
    const float* b1f = biasblk;
    const float* b2f = biasblk + 128;
    const float* cb1f = biasblk + 256;
    const float* cw2f = biasblk + 384;
    const float* ib1f = biasblk + 512;
    const float* iw2f = biasblk + 576;
    const float ib2s = biasblk[640];

    const int tid = threadIdx.x;
    const int wv = tid >> 6;
    const int lane = tid & 63;
    const int n15 = lane & 15;
    const int quad = lane >> 4;
    const int wb = blockIdx.x * 128 + wv * 32;

    int row_e[2], col_e[2];
    float dist[2], attr[2];
#pragma unroll
    for (int m = 0; m < 2; ++m) {
        int e = wb + m * 16 + n15;
        int eL = (e < E) ? e : (E - 1);
        row_e[m] = erow[eL];
        col_e[m] = ecol[eL];
        float d = 0.f;
#pragma unroll
        for (int dd = 0; dd < 3; ++dd) {
            float xd = xf[row_e[m] * 3 + dd] - xf[col_e[m] * 3 + dd];
            d += xd * xd;
        }
        dist[m] = d;
        attr[m] = eaf[eL];
    }

    // ---- GEMM1: ef[32 x 288] @ W1
    f32x4 acc1[2][8];
#pragma unroll
    for (int m = 0; m < 2; ++m)
#pragma unroll
        for (int nt = 0; nt < 8; ++nt) acc1[m][nt] = (f32x4){0.f, 0.f, 0.f, 0.f};

    for (int s = 0; s < 5; ++s) {
        const int k0 = s * 64;
        const int wk = (s < 4) ? 64 : 32;
        __syncthreads();
        stage_w(W1t, 288, k0, 128, wk, sW, tid);
        __syncthreads();
        const int kcs = (s < 4) ? 2 : 1;
        for (int kc2 = 0; kc2 < kcs; ++kc2) {
            const int kglob = k0 + kc2 * 32;
            short8 a[2];
#pragma unroll
            for (int m = 0; m < 2; ++m) {
                if (kglob < 128) {
                    a[m] = *(const short8*)(hb + row_e[m] * 128 + kglob + quad * 8);
                } else if (kglob < 256) {
                    a[m] = *(const short8*)(hb + col_e[m] * 128 + (kglob - 128) + quad * 8);
                } else {
#pragma unroll
                    for (int t = 0; t < 8; ++t) a[m][t] = 0;
                    if (quad == 0) { a[m][0] = f2bs_rn(dist[m]); a[m][1] = f2bs_rn(attr[m]); }
                }
            }
#pragma unroll
            for (int nt = 0; nt < 8; ++nt) {
                short8 b = *(const short8*)(sW + (nt * 16 + n15) * 72 + kc2 * 32 + quad * 8);
                acc1[0][nt] = __builtin_amdgcn_mfma_f32_16x16x32_bf16(a[0], b, acc1[0][nt], 0, 0, 0);
                acc1[1][nt] = __builtin_amdgcn_mfma_f32_16x16x32_bf16(a[1], b, acc1[1][nt], 0, 0, 0);
            }
        }
    }

    // ---- per-m pipeline
    short* tl = tiles[wv];
    for (int m = 0; m < 2; ++m) {
        // hidden1 -> wave-private tile (C->A transpose)
#pragma unroll
        for (int nt = 0; nt < 8; ++nt) {
            float bv = b1f[nt * 16 + n15];
#pragma unroll
            for (int r = 0; r < 4; ++r)
                tl[(quad * 4 + r) * 136 + nt * 16 + n15] = f2bs_rn(siluf(acc1[m][nt][r] + bv));
        }

        // GEMM2: hidden1 @ W2 -> m_ij
        f32x4 acc2[8];
#pragma unroll
        for (int nt = 0; nt < 8; ++nt) acc2[nt] = (f32x4){0.f, 0.f, 0.f, 0.f};
        for (int s = 0; s < 2; ++s) {
            __syncthreads();
            stage_w(W2t, 128, s * 64, 128, 64, sW, tid);
            __syncthreads();
            for (int kc2 = 0; kc2 < 2; ++kc2) {
                const int kc = s * 2 + kc2;
                short8 a = *(const short8*)(tl + n15 * 136 + kc * 32 + quad * 8);
#pragma unroll
                for (int nt = 0; nt < 8; ++nt) {
                    short8 b = *(const short8*)(sW + (nt * 16 + n15) * 72 + kc2 * 32 + quad * 8);
                    acc2[nt] = __builtin_amdgcn_mfma_f32_16x16x32_bf16(a, b, acc2[nt], 0, 0, 0);
                }
            }
        }

        // m_ij epilogue: rewrite tile, store raw m_ij (bf16) / keep for atomics
        float mvA[8][4];
#pragma unroll
        for (int nt = 0; nt < 8; ++nt) {
            float bv = b2f[nt * 16 + n15];
#pragma unroll
            for (int r = 0; r < 4; ++r) {
                float v = siluf(acc2[nt][r] + bv);
                short vb = f2bs_rn(v);
                tl[(quad * 4 + r) * 136 + nt * 16 + n15] = vb;
                if (ATOMIC) {
                    mvA[nt][r] = v;
                } else {
                    int eg = wb + m * 16 + quad * 4 + r;
                    if (eg < E) mbuf[(size_t)eg * 128 + nt * 16 + n15] = vb;
                }
            }
        }

        // GEMM4: inf hidden (64 cols) -> eij
        f32x4 acc4[4];
#pragma unroll
        for (int nt = 0; nt < 4; ++nt) acc4[nt] = (f32x4){0.f, 0.f, 0.f, 0.f};
        for (int s = 0; s < 2; ++s) {
            __syncthreads();
            stage_w(iW1t, 128, s * 64, 64, 64, sW, tid);
            __syncthreads();
            for (int kc2 = 0; kc2 < 2; ++kc2) {
                const int kc = s * 2 + kc2;
                short8 a = *(const short8*)(tl + n15 * 136 + kc * 32 + quad * 8);
#pragma unroll
                for (int nt = 0; nt < 4; ++nt) {
                    short8 b = *(const short8*)(sW + (nt * 16 + n15) * 72 + kc2 * 32 + quad * 8);
                    acc4[nt] = __builtin_amdgcn_mfma_f32_16x16x32_bf16(a, b, acc4[nt], 0, 0, 0);
                }
            }
        }
        float inp[4] = {0.f, 0.f, 0.f, 0.f};
#pragma unroll
        for (int nt = 0; nt < 4; ++nt) {
            float ib = ib1f[nt * 16 + n15];
            float iw = iw2f[nt * 16 + n15];
#pragma unroll
            for (int r = 0; r < 4; ++r) inp[r] += siluf(acc4[nt][r] + ib) * iw;
        }
#pragma unroll
        for (int mk = 1; mk < 16; mk <<= 1)
#pragma unroll
            for (int r = 0; r < 4; ++r) inp[r] += __shfl_xor(inp[r], mk);
        float eij[4];
#pragma unroll
        for (int r = 0; r < 4; ++r) eij[r] = sigmf(inp[r] + ib2s);

        // GEMM3: coord hidden -> phi
        f32x4 acc3[8];
#pragma unroll
        for (int nt = 0; nt < 8; ++nt) acc3[nt] = (f32x4){0.f, 0.f, 0.f, 0.f};
        for (int s = 0; s < 2; ++s) {
            __syncthreads();
            stage_w(cW1t, 128, s * 64, 128, 64, sW, tid);
            __syncthreads();
            for (int kc2 = 0; kc2 < 2; ++kc2) {
                const int kc = s * 2 + kc2;
                short8 a = *(const short8*)(tl + n15 * 136 + kc * 32 + quad * 8);
#pragma unroll
                for (int nt = 0; nt < 8; ++nt) {
                    short8 b = *(const short8*)(sW + (nt * 16 + n15) * 72 + kc2 * 32 + quad * 8);
                    acc3[nt] = __builtin_amdgcn_mfma_f32_16x16x32_bf16(a, b, acc3[nt], 0, 0, 0);
                }
            }
        }
        float php[4] = {0.f, 0.f, 0.f, 0.f};
#pragma unroll
        for (int nt = 0; nt < 8; ++nt) {
            float cb = cb1f[nt * 16 + n15];
            float cw = cw2f[nt * 16 + n15];
#pragma unroll
            for (int r = 0; r < 4; ++r) php[r] += siluf(acc3[nt][r] + cb) * cw;
        }
#pragma unroll
        for (int mk = 1; mk < 16; mk <<= 1)
#pragma unroll
            for (int r = 0; r < 4; ++r) php[r] += __shfl_xor(php[r], mk);

        int er[4], ec[4];
        bool mk4[4];
#pragma unroll
        for (int r = 0; r < 4; ++r) {
            er[r] = __shfl(row_e[m], quad * 4 + r);
            ec[r] = __shfl(col_e[m], quad * 4 + r);
            mk4[r] = (wb + m * 16 + quad * 4 + r) < E;
        }

        if (ATOMIC) {
#pragma unroll
            for (int nt = 0; nt < 8; ++nt)
#pragma unroll
                for (int r = 0; r < 4; ++r)
                    if (mk4[r]) atomicAdd(&m_i[er[r] * 128 + nt * 16 + n15],
                                          nz(eij[r] * mvA[nt][r]));
            if (n15 == 0) {
#pragma unroll
                for (int r = 0; r < 4; ++r) {
                    if (!mk4[r]) continue;
                    float s = eij[r] * php[r];
#pragma unroll
                    for (int d = 0; d < 3; ++d) {
                        float xd = xf[er[r] * 3 + d] - xf[ec[r] * 3 + d];
                        atomicAdd(&agg_x[er[r] * 3 + d], nz(s * xd));
                    }
                }
            }
        } else {
            if (n15 < 4) {
#pragma unroll
                for (int r = 0; r < 4; ++r) {
                    if (!mk4[r]) continue;
                    int eg = wb + m * 16 + quad * 4 + r;
                    if (n15 < 3) {
                        float xd = xf[er[r] * 3 + n15] - xf[ec[r] * 3 + n15];
                        xbuf[(size_t)eg * 4 + n15] = nz(eij[r] * php[r] * xd);
                    } else {
                        xbuf[(size_t)eg * 4 + 3] = eij[r];
                    }
                }
            }
        }
    }
}

// ---------------------------------------------------------------------------
// node kernel: 512 thr = 4 slots x 128, 8 nodes/block.  Gather applies eij
// (xbuf[.3]) to raw bf16 m_ij rows.  Transposed bf16 weights, short8 loads.
// ---------------------------------------------------------------------------
template <bool GATHER>
__global__ __launch_bounds__(512) void node_kernel(
    const short* __restrict__ hb, const float* __restrict__ xf,
    const void* __restrict__ v_init,
    const short* __restrict__ mbuf, const float* __restrict__ xbuf,
    const int* __restrict__ off, const int* __restrict__ cnt,
    const int* __restrict__ elist,
    const float* __restrict__ m_i, const float* __restrict__ agg_x,
    const short* __restrict__ nW1T, const short* __restrict__ nW2T,
    const short* __restrict__ vW1T, const float* __restrict__ biasblk,
    void* __restrict__ out, int N, int xbase, int vbase, float inv_nm1,
    const int* __restrict__ flagp) {
    const int flag = *flagp;
    const float* nb1f = biasblk + 644;
    const float* nb2f = biasblk + 772;
    const float* vb1f = biasblk + 900;
    const float* vW2f = biasblk + 1028;
    __shared__ float nin[4][256];
    __shared__ float red[4][128];
    __shared__ float hid[4][128];
    const int slot = threadIdx.x >> 7;
    const int j = threadIdx.x & 127;

    for (int it = 0; it < 2; ++it) {
        const int n = blockIdx.x * 8 + it * 4 + slot;
        const bool act = (n < N);
        const int na = act ? n : (N - 1);

        nin[slot][j] = bs2f(hb[na * 128 + j]);
        const int c = cnt[na];
        float msum = 0.f;
        if (GATHER) {
            const int s0 = off[na];
            for (int i = 0; i < c; ++i) {
                int eid = elist[s0 + i];
                float ev = xbuf[(size_t)eid * 4 + 3];
                msum += ev * bs2f(mbuf[(size_t)eid * 128 + j]);
            }
        } else {
            msum = m_i[na * 128 + j];
        }
        nin[slot][128 + j] = nz(msum);
        __syncthreads();

        // vel MLP
        float vacc = vb1f[j];
        for (int k0 = 0; k0 < 128; k0 += 8) {
            short8 w = *(const short8*)(vW1T + j * 128 + k0);
#pragma unroll
            for (int t = 0; t < 8; ++t) vacc += nin[slot][k0 + t] * bs2f(w[t]);
        }
        red[slot][j] = siluf(vacc) * vW2f[j];
        __syncthreads();
        for (int s = 64; s > 0; s >>= 1) {
            if (j < s) red[slot][j] += red[slot][j + s];
            __syncthreads();
        }
        const float vscale = red[slot][0];

        // node MLP
        float acc = nb1f[j];
        for (int k0 = 0; k0 < 256; k0 += 8) {
            short8 w = *(const short8*)(nW1T + j * 256 + k0);
#pragma unroll
            for (int t = 0; t < 8; ++t) acc += nin[slot][k0 + t] * bs2f(w[t]);
        }
        hid[slot][j] = siluf(acc);
        __syncthreads();
        float o = nb2f[j];
        for (int k0 = 0; k0 < 128; k0 += 8) {
            short8 w = *(const short8*)(nW2T + j * 128 + k0);
#pragma unroll
            for (int t = 0; t < 8; ++t) o += hid[slot][k0 + t] * bs2f(w[t]);
        }
        if (act) stf(out, n * 128 + j, nz(o), flag);

        if (act && j < 3) {
            float vj = nz(ldf(v_init, n * 3 + j, flag) * vscale);
            stf(out, vbase + n * 3 + j, vj, flag);
            float xv = xf[n * 3 + j];
            float ax;
            if (GATHER) {
                ax = 0.f;
                const int s0 = off[na];
                for (int i = 0; i < c; ++i) {
                    int eid = elist[s0 + i];
                    ax += xbuf[(size_t)eid * 4 + j];
                }
            } else {
                ax = agg_x[n * 3 + j];
            }
            float xo = (c > 0) ? xv + vj + nz(ax) * inv_nm1 : xv;
            stf(out, xbase + n * 3 + j, nz(xo), flag);
        }
        __syncthreads();
    }
}

// ---------------------------------------------------------------------------
extern "C" void kernel_launch(void* const* d_in, const int* in_sizes, int n_in,
                              void* d_out, int out_size, void* d_ws, size_t ws_size,
                              hipStream_t stream) {
    const void* h = d_in[0];
    const void* x = d_in[1];
    const void* eattr = d_in[2];
    const void* v_init = d_in[3];
    const int* eidx = (const int*)d_in[4];

    const int N = in_sizes[0] / 128;
    const int E = in_sizes[4] / 2;
    const int* erow = eidx;
    const int* ecol = eidx + E;

    char* ws = (char*)d_ws;
    int* flag = (int*)ws;                       // 256
    short* W1t = (short*)(ws + 256);            // 73728
    short* W2t = (short*)(ws + 73984);          // 32768
    short* cW1t = (short*)(ws + 106752);        // 32768
    short* iW1t = (short*)(ws + 139520);        // 16384
    float* biasblk = (float*)(ws + 155904);     // 4624 -> pad 160768
    short* nW1T = (short*)(ws + 160768);        // 65536
    short* nW2T = (short*)(ws + 226304);        // 32768
    short* vW1T = (short*)(ws + 259072);        // 32768
    int* bsum = (int*)(ws + 291840);            // 512
    int* bpre = (int*)(ws + 292352);            // 512
    short* hb = (short*)(ws + 292864);          // N*256
    size_t o = 292864 + (size_t)N * 256;
    float* xf = (float*)(ws + o); o += (size_t)N * 12;
    float* eaf = (float*)(ws + o); o += (size_t)E * 4;
    size_t oCnt = o;
    int* cnt = (int*)(ws + o); o += (size_t)N * 4;
    // big path
    size_t oCur = o;
    int* cur = (int*)(ws + o); o += (size_t)N * 4;
    int* offp = (int*)(ws + o); o += (size_t)(N + 16) * 4;
    int* elist = (int*)(ws + o); o += (size_t)E * 4;
    float* xbuf = (float*)(ws + o); o += (size_t)E * 16;
    short* mbuf = (short*)(ws + o); o += (size_t)E * 256;
    const size_t need_big = o;
    // fallback overlay (after cnt)
    float* fb_agg = (float*)(ws + oCur);
    float* fb_mi = (float*)(ws + oCur + (size_t)N * 16);

    const bool big = (ws_size >= need_big);

    detect_kernel<<<1, 64, 0, stream>>>((const unsigned int*)h, flag);

    const int prep_elems = 36864 + 16384 + 16384 + 8192 + 1156 + 32768 + 16384 + 16384;
    prep_kernel<<<(prep_elems + 255) / 256, 256, 0, stream>>>(
        d_in[5], d_in[7], d_in[9], d_in[12],
        d_in[6], d_in[8], d_in[10], d_in[11], d_in[13], d_in[14], d_in[15],
        d_in[17], d_in[19], d_in[21], d_in[22],
        d_in[16], d_in[18], d_in[20],
        W1t, W2t, cW1t, iW1t, biasblk, nW1T, nW2T, vW1T, flag);

    convh_kernel<<<(N * 128 + 255) / 256, 256, 0, stream>>>(h, hb, flag, N * 128);
    convaux_kernel<<<(N * 3 + E + 255) / 256, 256, 0, stream>>>(x, eattr, xf, eaf, flag,
                                                               N * 3, E);

    if (big) {
        hipMemsetAsync((void*)(ws + oCnt), 0, (size_t)N * 8, stream);  // cnt+cur
        count_kernel<<<(E + 255) / 256, 256, 0, stream>>>(erow, cnt, E);
        const int nb = (N + 1023) / 1024;
        scan1_kernel<<<nb, 1024, 0, stream>>>(cnt, offp, bsum, N);
        scan2_kernel<<<1, 64, 0, stream>>>(bsum, bpre, nb);
        scan3_kernel<<<(N + 255) / 256, 256, 0, stream>>>(offp, bpre, N);
        fill_kernel<<<(E + 255) / 256, 256, 0, stream>>>(erow, offp, cur, elist, E);

        edge_kernel<false><<<(E + 127) / 128, 256, 0, stream>>>(
            hb, xf, eaf, erow, ecol, W1t, W2t, cW1t, iW1t, biasblk,
            mbuf, xbuf, nullptr, nullptr, E);

        node_kernel<true><<<(N + 7) / 8, 512, 0, stream>>>(
            hb, xf, v_init, mbuf, xbuf, offp, cnt, elist, nullptr, nullptr,
            nW1T, nW2T, vW1T, biasblk, d_out, N, N * 128, N * 131,
            1.0f / (float)(N - 1), flag);
    } else {
        hipMemsetAsync((void*)(ws + oCnt), 0, (size_t)N * 4 + (size_t)N * 16 + (size_t)N * 512,
                       stream);
        count_kernel<<<(E + 255) / 256, 256, 0, stream>>>(erow, cnt, E);

        edge_kernel<true><<<(E + 127) / 128, 256, 0, stream>>>(
            hb, xf, eaf, erow, ecol, W1t, W2t, cW1t, iW1t, biasblk,
            nullptr, nullptr, fb_mi, fb_agg, E);

        node_kernel<false><<<(N + 7) / 8, 512, 0, stream>>>(
            hb, xf, v_init, nullptr, nullptr, nullptr, cnt, nullptr, fb_mi, fb_agg,
            nW1T, nW2T, vW1T, biasblk, d_out, N, N * 128, N * 131,
            1.0f / (float)(N - 1), flag);
    }
}

// Round 7
// 1708.727 us; speedup vs baseline: 2.8069x; 2.8069x over previous
//
#include <hip/hip_runtime.h>
#include <hip/hip_bf16.h>

typedef __attribute__((ext_vector_type(8))) short short8;
typedef __attribute__((ext_vector_type(4))) float f32x4;
typedef __hip_bfloat16 bf16;

__device__ __forceinline__ short f2bs_rn(float f) {   // fast RNE bf16 pack
    unsigned u = __builtin_bit_cast(unsigned, f);
    u += 0x7FFF + ((u >> 16) & 1);
    return (short)(u >> 16);
}
__device__ __forceinline__ float bs2f(short s) {
    unsigned u = ((unsigned)(unsigned short)s) << 16;
    return __builtin_bit_cast(float, u);
}
__device__ __forceinline__ float ldf(const void* p, int i, int flag) {
    return flag ? bs2f(((const short*)p)[i]) : ((const float*)p)[i];
}
__device__ __forceinline__ short ldbits(const void* p, int i, int flag) {
    return flag ? ((const short*)p)[i] : f2bs_rn(((const float*)p)[i]);
}
__device__ __forceinline__ void stf(void* p, int i, float v, int flag) {
    if (flag) ((bf16*)p)[i] = __float2bfloat16(v);
    else ((float*)p)[i] = v;
}
__device__ __forceinline__ float nz(float v) { return (v == v) ? v : 0.f; }
// rcp-based: exact limits at +-inf, no fp32 div chain
__device__ __forceinline__ float siluf(float v) {
    return v * __builtin_amdgcn_rcpf(1.f + __expf(-v));
}
__device__ __forceinline__ float sigmf(float v) {
    return __builtin_amdgcn_rcpf(1.f + __expf(-v));
}

// ---------------------------------------------------------------------------
__global__ void detect_kernel(const unsigned int* __restrict__ hw, int* __restrict__ flag) {
    unsigned int w = hw[threadIdx.x];
    unsigned int e = (w >> 7) & 0xFF;
    bool ok = (e >= 113 && e <= 135);
    unsigned long long m = __ballot(ok);
    if (threadIdx.x == 0) *flag = (__popcll(m) >= 32) ? 1 : 0;
}

// ---------------------------------------------------------------------------
// prep: transposed bf16 edge weights; fp32 bias block; bf16 node/vel weights
// in ORIGINAL [k][j] layout (coalesced column reads in node kernel).
// ---------------------------------------------------------------------------
__global__ void prep_kernel(
    const void* eW1, const void* eW2, const void* cW1, const void* iW1,
    const void* eb1, const void* eb2, const void* cb1, const void* cw2,
    const void* ib1, const void* iw2, const void* ib2, const void* nb1,
    const void* nb2, const void* vb1, const void* vW2,
    const void* nW1, const void* nW2, const void* vW1,
    short* __restrict__ W1t, short* __restrict__ W2t,
    short* __restrict__ cW1t, short* __restrict__ iW1t,
    float* __restrict__ biasblk, short* __restrict__ nW1b,
    short* __restrict__ nW2b, short* __restrict__ vW1b,
    const int* __restrict__ flagp) {
    const int flag = *flagp;
    int i = blockIdx.x * 256 + threadIdx.x;
    if (i < 36864) { int n = i / 288, k = i % 288; W1t[i] = (k < 258) ? ldbits(eW1, k * 128 + n, flag) : (short)0; return; }
    i -= 36864;
    if (i < 16384) { int n = i / 128, k = i % 128; W2t[i] = ldbits(eW2, k * 128 + n, flag); return; }
    i -= 16384;
    if (i < 16384) { int n = i / 128, k = i % 128; cW1t[i] = ldbits(cW1, k * 128 + n, flag); return; }
    i -= 16384;
    if (i < 8192) { int n = i / 128, k = i % 128; iW1t[i] = ldbits(iW1, k * 64 + n, flag); return; }
    i -= 8192;
    if (i < 1156) {
        float v;
        if (i < 128) v = ldf(eb1, i, flag);
        else if (i < 256) v = ldf(eb2, i - 128, flag);
        else if (i < 384) v = ldf(cb1, i - 256, flag);
        else if (i < 512) v = ldf(cw2, i - 384, flag);
        else if (i < 576) v = ldf(ib1, i - 512, flag);
        else if (i < 640) v = ldf(iw2, i - 576, flag);
        else if (i < 644) v = (i == 640) ? ldf(ib2, 0, flag) : 0.f;
        else if (i < 772) v = ldf(nb1, i - 644, flag);
        else if (i < 900) v = ldf(nb2, i - 772, flag);
        else if (i < 1028) v = ldf(vb1, i - 900, flag);
        else v = ldf(vW2, i - 1028, flag);
        biasblk[i] = v;
        return;
    }
    i -= 1156;
    if (i < 32768) { nW1b[i] = ldbits(nW1, i, flag); return; }
    i -= 32768;
    if (i < 16384) { nW2b[i] = ldbits(nW2, i, flag); return; }
    i -= 16384;
    if (i < 16384) { vW1b[i] = ldbits(vW1, i, flag); }
}

// ---------------------------------------------------------------------------
__global__ void convh_kernel(const void* __restrict__ h, short* __restrict__ hb,
                             const int* __restrict__ flagp, int n) {
    const int flag = *flagp;
    int i = blockIdx.x * 256 + threadIdx.x;
    if (i < n) hb[i] = ldbits(h, i, flag);
}

__global__ void convaux_kernel(const void* __restrict__ x, const void* __restrict__ ea,
                               float* __restrict__ xf, float* __restrict__ eaf,
                               const int* __restrict__ flagp, int nx, int ne) {
    const int flag = *flagp;
    int i = blockIdx.x * 256 + threadIdx.x;
    if (i < nx) { xf[i] = ldf(x, i, flag); return; }
    i -= nx;
    if (i < ne) eaf[i] = ldf(ea, i, flag);
}

// ---------------------------------------------------------------------------
// CSR build
// ---------------------------------------------------------------------------
__global__ void count_kernel(const int* __restrict__ erow, int* __restrict__ cnt, int E) {
    int i = blockIdx.x * 256 + threadIdx.x;
    if (i < E) atomicAdd(&cnt[erow[i]], 1);
}

__global__ __launch_bounds__(1024) void scan1_kernel(const int* __restrict__ cnt,
                                                     int* __restrict__ off,
                                                     int* __restrict__ bsum, int N) {
    __shared__ int sm[1024];
    int t = threadIdx.x, i = blockIdx.x * 1024 + t;
    int c = (i < N) ? cnt[i] : 0;
    sm[t] = c;
    __syncthreads();
    for (int d = 1; d < 1024; d <<= 1) {
        int v = (t >= d) ? sm[t - d] : 0;
        __syncthreads();
        sm[t] += v;
        __syncthreads();
    }
    if (i < N) off[i] = sm[t] - c;
    if (t == 1023) bsum[blockIdx.x] = sm[1023];
}
__global__ void scan2_kernel(const int* __restrict__ bsum, int* __restrict__ bpre, int nb) {
    if (threadIdx.x == 0) {
        int run = 0;
        for (int b = 0; b < nb; ++b) { bpre[b] = run; run += bsum[b]; }
    }
}
__global__ void scan3_kernel(int* __restrict__ off, const int* __restrict__ bpre, int N) {
    int i = blockIdx.x * 256 + threadIdx.x;
    if (i < N) off[i] += bpre[i >> 10];
}
__global__ void fill_kernel(const int* __restrict__ erow, const int* __restrict__ off,
                            int* __restrict__ cur, int* __restrict__ elist, int E) {
    int i = blockIdx.x * 256 + threadIdx.x;
    if (i < E) {
        int r = erow[i];
        int p = off[r] + atomicAdd(&cur[r], 1);
        elist[p] = i;
    }
}

// ---------------------------------------------------------------------------
// edge kernel: round-5 structure — 4 waves x 32 edges, all GEMMs for both
// m-tiles share each staged weight slice (11 stagings/block).
// mbuf stores bf16(e_ij * m_ij) — gather is a plain sum.
// ---------------------------------------------------------------------------
__device__ __forceinline__ void stage_w(const short* __restrict__ src, int grs, int k0,
                                        int nrows, int wk, short* __restrict__ sW, int tid) {
    const int upr = wk >> 3;
    const int units = nrows * upr;
    for (int u = tid; u < units; u += 256) {
        int n = u / upr, c = u % upr;
        *(short8*)(sW + n * 72 + c * 8) = *(const short8*)(src + n * grs + k0 + c * 8);
    }
}

template <bool ATOMIC>
__global__ __launch_bounds__(256, 2) void edge_kernel(
    const short* __restrict__ hb, const float* __restrict__ xf,
    const float* __restrict__ eaf,
    const int* __restrict__ erow, const int* __restrict__ ecol,
    const short* __restrict__ W1t, const short* __restrict__ W2t,
    const short* __restrict__ cW1t, const short* __restrict__ iW1t,
    const float* __restrict__ biasblk,
    short* __restrict__ mbuf, float* __restrict__ xbuf,
    float* __restrict__ m_i, float* __restrict__ agg_x, int E) {
    __shared__ __align__(16) short sW[128 * 72];        // 18432 B
    __shared__ __align__(16) short tiles[8][16 * 136];  // 34816 B
    const float* b1f = biasblk;
    const float* b2f = biasblk + 128;
    const float* cb1f = biasblk + 256;
    const float* cw2f = biasblk + 384;
    const float* ib1f = biasblk + 512;
    const float* iw2f = biasblk + 576;
    const float ib2s = biasblk[640];

    const int tid = threadIdx.x;
    const int wv = tid >> 6;
    const int lane = tid & 63;
    const int n15 = lane & 15;
    const int quad = lane >> 4;
    const int wb = blockIdx.x * 128 + wv * 32;

    int row_e[2], col_e[2];
    float dist[2], attr[2];
#pragma unroll
    for (int m = 0; m < 2; ++m) {
        int e = wb + m * 16 + n15;
        int eL = (e < E) ? e : (E - 1);
        row_e[m] = erow[eL];
        col_e[m] = ecol[eL];
        float d = 0.f;
#pragma unroll
        for (int dd = 0; dd < 3; ++dd) {
            float xd = xf[row_e[m] * 3 + dd] - xf[col_e[m] * 3 + dd];
            d += xd * xd;
        }
        dist[m] = d;
        attr[m] = eaf[eL];
    }

    // ---- GEMM1: ef[32 x 288] @ W1
    f32x4 acc1[2][8];
#pragma unroll
    for (int m = 0; m < 2; ++m)
#pragma unroll
        for (int nt = 0; nt < 8; ++nt) acc1[m][nt] = (f32x4){0.f, 0.f, 0.f, 0.f};

    for (int s = 0; s < 5; ++s) {
        const int k0 = s * 64;
        const int wk = (s < 4) ? 64 : 32;
        __syncthreads();
        stage_w(W1t, 288, k0, 128, wk, sW, tid);
        __syncthreads();
        const int kcs = (s < 4) ? 2 : 1;
        for (int kc2 = 0; kc2 < kcs; ++kc2) {
            const int kglob = k0 + kc2 * 32;
            short8 a[2];
#pragma unroll
            for (int m = 0; m < 2; ++m) {
                if (kglob < 128) {
                    a[m] = *(const short8*)(hb + row_e[m] * 128 + kglob + quad * 8);
                } else if (kglob < 256) {
                    a[m] = *(const short8*)(hb + col_e[m] * 128 + (kglob - 128) + quad * 8);
                } else {
#pragma unroll
                    for (int t = 0; t < 8; ++t) a[m][t] = 0;
                    if (quad == 0) { a[m][0] = f2bs_rn(dist[m]); a[m][1] = f2bs_rn(attr[m]); }
                }
            }
#pragma unroll
            for (int nt = 0; nt < 8; ++nt) {
                short8 b = *(const short8*)(sW + (nt * 16 + n15) * 72 + kc2 * 32 + quad * 8);
                acc1[0][nt] = __builtin_amdgcn_mfma_f32_16x16x32_bf16(a[0], b, acc1[0][nt], 0, 0, 0);
                acc1[1][nt] = __builtin_amdgcn_mfma_f32_16x16x32_bf16(a[1], b, acc1[1][nt], 0, 0, 0);
            }
        }
    }

    // hidden1 -> per-wave tiles
#pragma unroll
    for (int m = 0; m < 2; ++m) {
        short* tl = tiles[wv * 2 + m];
#pragma unroll
        for (int nt = 0; nt < 8; ++nt) {
            float bv = b1f[nt * 16 + n15];
#pragma unroll
            for (int r = 0; r < 4; ++r)
                tl[(quad * 4 + r) * 136 + nt * 16 + n15] = f2bs_rn(siluf(acc1[m][nt][r] + bv));
        }
    }

    // ---- GEMM2: hidden1 @ W2 (2 slices, both m share)
    f32x4 acc2[2][8];
#pragma unroll
    for (int m = 0; m < 2; ++m)
#pragma unroll
        for (int nt = 0; nt < 8; ++nt) acc2[m][nt] = (f32x4){0.f, 0.f, 0.f, 0.f};
    for (int s = 0; s < 2; ++s) {
        __syncthreads();
        stage_w(W2t, 128, s * 64, 128, 64, sW, tid);
        __syncthreads();
        for (int kc2 = 0; kc2 < 2; ++kc2) {
            const int kc = s * 2 + kc2;
            short8 a[2];
#pragma unroll
            for (int m = 0; m < 2; ++m)
                a[m] = *(const short8*)(tiles[wv * 2 + m] + n15 * 136 + kc * 32 + quad * 8);
#pragma unroll
            for (int nt = 0; nt < 8; ++nt) {
                short8 b = *(const short8*)(sW + (nt * 16 + n15) * 72 + kc2 * 32 + quad * 8);
                acc2[0][nt] = __builtin_amdgcn_mfma_f32_16x16x32_bf16(a[0], b, acc2[0][nt], 0, 0, 0);
                acc2[1][nt] = __builtin_amdgcn_mfma_f32_16x16x32_bf16(a[1], b, acc2[1][nt], 0, 0, 0);
            }
        }
    }

    // m_ij -> mv regs + rewrite tiles
    float mv[2][8][4];
#pragma unroll
    for (int m = 0; m < 2; ++m) {
        short* tl = tiles[wv * 2 + m];
#pragma unroll
        for (int nt = 0; nt < 8; ++nt) {
            float bv = b2f[nt * 16 + n15];
#pragma unroll
            for (int r = 0; r < 4; ++r) {
                float v = siluf(acc2[m][nt][r] + bv);
                mv[m][nt][r] = v;
                tl[(quad * 4 + r) * 136 + nt * 16 + n15] = f2bs_rn(v);
            }
        }
    }

    // ---- GEMM4 (inf, 64 cols) -> eij
    f32x4 acc4[2][4];
#pragma unroll
    for (int m = 0; m < 2; ++m)
#pragma unroll
        for (int nt = 0; nt < 4; ++nt) acc4[m][nt] = (f32x4){0.f, 0.f, 0.f, 0.f};
    for (int s = 0; s < 2; ++s) {
        __syncthreads();
        stage_w(iW1t, 128, s * 64, 64, 64, sW, tid);
        __syncthreads();
        for (int kc2 = 0; kc2 < 2; ++kc2) {
            const int kc = s * 2 + kc2;
            short8 a[2];
#pragma unroll
            for (int m = 0; m < 2; ++m)
                a[m] = *(const short8*)(tiles[wv * 2 + m] + n15 * 136 + kc * 32 + quad * 8);
#pragma unroll
            for (int nt = 0; nt < 4; ++nt) {
                short8 b = *(const short8*)(sW + (nt * 16 + n15) * 72 + kc2 * 32 + quad * 8);
                acc4[0][nt] = __builtin_amdgcn_mfma_f32_16x16x32_bf16(a[0], b, acc4[0][nt], 0, 0, 0);
                acc4[1][nt] = __builtin_amdgcn_mfma_f32_16x16x32_bf16(a[1], b, acc4[1][nt], 0, 0, 0);
            }
        }
    }
    float eij[2][4];
#pragma unroll
    for (int m = 0; m < 2; ++m) {
        float inp[4] = {0.f, 0.f, 0.f, 0.f};
#pragma unroll
        for (int nt = 0; nt < 4; ++nt) {
            float ib = ib1f[nt * 16 + n15];
            float iw = iw2f[nt * 16 + n15];
#pragma unroll
            for (int r = 0; r < 4; ++r) inp[r] += siluf(acc4[m][nt][r] + ib) * iw;
        }
#pragma unroll
        for (int mk = 1; mk < 16; mk <<= 1)
#pragma unroll
            for (int r = 0; r < 4; ++r) inp[r] += __shfl_xor(inp[r], mk);
#pragma unroll
        for (int r = 0; r < 4; ++r) eij[m][r] = sigmf(inp[r] + ib2s);
    }

    // ---- GEMM3 (coord) -> phi
    f32x4 acc3[2][8];
#pragma unroll
    for (int m = 0; m < 2; ++m)
#pragma unroll
        for (int nt = 0; nt < 8; ++nt) acc3[m][nt] = (f32x4){0.f, 0.f, 0.f, 0.f};
    for (int s = 0; s < 2; ++s) {
        __syncthreads();
        stage_w(cW1t, 128, s * 64, 128, 64, sW, tid);
        __syncthreads();
        for (int kc2 = 0; kc2 < 2; ++kc2) {
            const int kc = s * 2 + kc2;
            short8 a[2];
#pragma unroll
            for (int m = 0; m < 2; ++m)
                a[m] = *(const short8*)(tiles[wv * 2 + m] + n15 * 136 + kc * 32 + quad * 8);
#pragma unroll
            for (int nt = 0; nt < 8; ++nt) {
                short8 b = *(const short8*)(sW + (nt * 16 + n15) * 72 + kc2 * 32 + quad * 8);
                acc3[0][nt] = __builtin_amdgcn_mfma_f32_16x16x32_bf16(a[0], b, acc3[0][nt], 0, 0, 0);
                acc3[1][nt] = __builtin_amdgcn_mfma_f32_16x16x32_bf16(a[1], b, acc3[1][nt], 0, 0, 0);
            }
        }
    }

    // ---- stores per m-tile
#pragma unroll
    for (int m = 0; m < 2; ++m) {
        float php[4] = {0.f, 0.f, 0.f, 0.f};
#pragma unroll
        for (int nt = 0; nt < 8; ++nt) {
            float cb = cb1f[nt * 16 + n15];
            float cw = cw2f[nt * 16 + n15];
#pragma unroll
            for (int r = 0; r < 4; ++r) php[r] += siluf(acc3[m][nt][r] + cb) * cw;
        }
#pragma unroll
        for (int mk = 1; mk < 16; mk <<= 1)
#pragma unroll
            for (int r = 0; r < 4; ++r) php[r] += __shfl_xor(php[r], mk);

        int er[4], ec[4];
        bool mk4[4];
#pragma unroll
        for (int r = 0; r < 4; ++r) {
            er[r] = __shfl(row_e[m], quad * 4 + r);
            ec[r] = __shfl(col_e[m], quad * 4 + r);
            mk4[r] = (wb + m * 16 + quad * 4 + r) < E;
        }
        if (ATOMIC) {
#pragma unroll
            for (int nt = 0; nt < 8; ++nt)
#pragma unroll
                for (int r = 0; r < 4; ++r)
                    if (mk4[r]) atomicAdd(&m_i[er[r] * 128 + nt * 16 + n15],
                                          nz(eij[m][r] * mv[m][nt][r]));
            if (n15 == 0) {
#pragma unroll
                for (int r = 0; r < 4; ++r) {
                    if (!mk4[r]) continue;
                    float s = eij[m][r] * php[r];
#pragma unroll
                    for (int d = 0; d < 3; ++d) {
                        float xd = xf[er[r] * 3 + d] - xf[ec[r] * 3 + d];
                        atomicAdd(&agg_x[er[r] * 3 + d], nz(s * xd));
                    }
                }
            }
        } else {
#pragma unroll
            for (int nt = 0; nt < 8; ++nt)
#pragma unroll
                for (int r = 0; r < 4; ++r)
                    if (mk4[r])
                        mbuf[(size_t)(wb + m * 16 + quad * 4 + r) * 128 + nt * 16 + n15] =
                            f2bs_rn(nz(eij[m][r] * mv[m][nt][r]));
            if (n15 < 3) {
#pragma unroll
                for (int r = 0; r < 4; ++r) {
                    if (!mk4[r]) continue;
                    float s = eij[m][r] * php[r];
                    float xd = xf[er[r] * 3 + n15] - xf[ec[r] * 3 + n15];
                    xbuf[(size_t)(wb + m * 16 + quad * 4 + r) * 4 + n15] = nz(s * xd);
                }
            }
        }
    }
}

// ---------------------------------------------------------------------------
// node kernel: round-5 structure. 512 thr = 4 slots x 128. Column-major
// bf16 weight loads (coalesced, low VGPR). Gather = plain sum of bf16 rows.
// ---------------------------------------------------------------------------
template <bool GATHER>
__global__ __launch_bounds__(512) void node_kernel(
    const short* __restrict__ hb, const float* __restrict__ xf,
    const void* __restrict__ v_init,
    const short* __restrict__ mbuf, const float* __restrict__ xbuf,
    const int* __restrict__ off, const int* __restrict__ cnt,
    const int* __restrict__ elist,
    const float* __restrict__ m_i, const float* __restrict__ agg_x,
    const short* __restrict__ nW1b, const short* __restrict__ nW2b,
    const short* __restrict__ vW1b, const float* __restrict__ biasblk,
    void* __restrict__ out, int N, int xbase, int vbase, float inv_nm1,
    const int* __restrict__ flagp) {
    const int flag = *flagp;
    const float* nb1f = biasblk + 644;
    const float* nb2f = biasblk + 772;
    const float* vb1f = biasblk + 900;
    const float* vW2f = biasblk + 1028;
    __shared__ float nin[4][256];
    __shared__ float red[4][128];
    __shared__ float hid[4][128];
    const int slot = threadIdx.x >> 7;
    const int j = threadIdx.x & 127;

    for (int it = 0; it < 2; ++it) {
        const int n = blockIdx.x * 8 + it * 4 + slot;
        const bool act = (n < N);
        const int na = act ? n : (N - 1);

        nin[slot][j] = bs2f(hb[na * 128 + j]);
        const int c = cnt[na];
        float msum = 0.f;
        if (GATHER) {
            const int s0 = off[na];
            for (int i = 0; i < c; ++i) {
                int eid = elist[s0 + i];
                msum += bs2f(mbuf[(size_t)eid * 128 + j]);
            }
        } else {
            msum = m_i[na * 128 + j];
        }
        nin[slot][128 + j] = nz(msum);
        __syncthreads();

        // vel MLP
        float vacc = vb1f[j];
#pragma unroll 8
        for (int k = 0; k < 128; ++k) vacc += nin[slot][k] * bs2f(vW1b[k * 128 + j]);
        red[slot][j] = siluf(vacc) * vW2f[j];
        __syncthreads();
        for (int s = 64; s > 0; s >>= 1) {
            if (j < s) red[slot][j] += red[slot][j + s];
            __syncthreads();
        }
        const float vscale = red[slot][0];

        // node MLP
        float acc = nb1f[j];
#pragma unroll 8
        for (int k = 0; k < 256; ++k) acc += nin[slot][k] * bs2f(nW1b[k * 128 + j]);
        hid[slot][j] = siluf(acc);
        __syncthreads();
        float o = nb2f[j];
#pragma unroll 8
        for (int k = 0; k < 128; ++k) o += hid[slot][k] * bs2f(nW2b[k * 128 + j]);
        if (act) stf(out, n * 128 + j, nz(o), flag);

        if (act && j < 3) {
            float vj = nz(ldf(v_init, n * 3 + j, flag) * vscale);
            stf(out, vbase + n * 3 + j, vj, flag);
            float xv = xf[n * 3 + j];
            float ax;
            if (GATHER) {
                ax = 0.f;
                const int s0 = off[na];
                for (int i = 0; i < c; ++i) {
                    int eid = elist[s0 + i];
                    ax += xbuf[(size_t)eid * 4 + j];
                }
            } else {
                ax = agg_x[n * 3 + j];
            }
            float xo = (c > 0) ? xv + vj + nz(ax) * inv_nm1 : xv;
            stf(out, xbase + n * 3 + j, nz(xo), flag);
        }
        __syncthreads();
    }
}

// ---------------------------------------------------------------------------
extern "C" void kernel_launch(void* const* d_in, const int* in_sizes, int n_in,
                              void* d_out, int out_size, void* d_ws, size_t ws_size,
                              hipStream_t stream) {
    const void* h = d_in[0];
    const void* x = d_in[1];
    const void* eattr = d_in[2];
    const void* v_init = d_in[3];
    const int* eidx = (const int*)d_in[4];

    const int N = in_sizes[0] / 128;
    const int E = in_sizes[4] / 2;
    const int* erow = eidx;
    const int* ecol = eidx + E;

    char* ws = (char*)d_ws;
    int* flag = (int*)ws;                       // 256
    short* W1t = (short*)(ws + 256);            // 73728
    short* W2t = (short*)(ws + 73984);          // 32768
    short* cW1t = (short*)(ws + 106752);        // 32768
    short* iW1t = (short*)(ws + 139520);        // 16384
    float* biasblk = (float*)(ws + 155904);     // 4624 -> pad 160768
    short* nW1b = (short*)(ws + 160768);        // 65536
    short* nW2b = (short*)(ws + 226304);        // 32768
    short* vW1b = (short*)(ws + 259072);        // 32768
    int* bsum = (int*)(ws + 291840);            // 512
    int* bpre = (int*)(ws + 292352);            // 512
    short* hb = (short*)(ws + 292864);          // N*256
    size_t o = 292864 + (size_t)N * 256;
    float* xf = (float*)(ws + o); o += (size_t)N * 12;
    float* eaf = (float*)(ws + o); o += (size_t)E * 4;
    size_t oCnt = o;
    int* cnt = (int*)(ws + o); o += (size_t)N * 4;
    // big path
    size_t oCur = o;
    int* cur = (int*)(ws + o); o += (size_t)N * 4;
    int* offp = (int*)(ws + o); o += (size_t)(N + 16) * 4;
    int* elist = (int*)(ws + o); o += (size_t)E * 4;
    float* xbuf = (float*)(ws + o); o += (size_t)E * 16;
    short* mbuf = (short*)(ws + o); o += (size_t)E * 256;
    const size_t need_big = o;
    // fallback overlay (after cnt)
    float* fb_agg = (float*)(ws + oCur);
    float* fb_mi = (float*)(ws + oCur + (size_t)N * 16);

    const bool big = (ws_size >= need_big);

    detect_kernel<<<1, 64, 0, stream>>>((const unsigned int*)h, flag);

    const int prep_elems = 36864 + 16384 + 16384 + 8192 + 1156 + 32768 + 16384 + 16384;
    prep_kernel<<<(prep_elems + 255) / 256, 256, 0, stream>>>(
        d_in[5], d_in[7], d_in[9], d_in[12],
        d_in[6], d_in[8], d_in[10], d_in[11], d_in[13], d_in[14], d_in[15],
        d_in[17], d_in[19], d_in[21], d_in[22],
        d_in[16], d_in[18], d_in[20],
        W1t, W2t, cW1t, iW1t, biasblk, nW1b, nW2b, vW1b, flag);

    convh_kernel<<<(N * 128 + 255) / 256, 256, 0, stream>>>(h, hb, flag, N * 128);
    convaux_kernel<<<(N * 3 + E + 255) / 256, 256, 0, stream>>>(x, eattr, xf, eaf, flag,
                                                               N * 3, E);

    if (big) {
        hipMemsetAsync((void*)(ws + oCnt), 0, (size_t)N * 8, stream);  // cnt+cur
        count_kernel<<<(E + 255) / 256, 256, 0, stream>>>(erow, cnt, E);
        const int nb = (N + 1023) / 1024;
        scan1_kernel<<<nb, 1024, 0, stream>>>(cnt, offp, bsum, N);
        scan2_kernel<<<1, 64, 0, stream>>>(bsum, bpre, nb);
        scan3_kernel<<<(N + 255) / 256, 256, 0, stream>>>(offp, bpre, N);
        fill_kernel<<<(E + 255) / 256, 256, 0, stream>>>(erow, offp, cur, elist, E);

        edge_kernel<false><<<(E + 127) / 128, 256, 0, stream>>>(
            hb, xf, eaf, erow, ecol, W1t, W2t, cW1t, iW1t, biasblk,
            mbuf, xbuf, nullptr, nullptr, E);

        node_kernel<true><<<(N + 7) / 8, 512, 0, stream>>>(
            hb, xf, v_init, mbuf, xbuf, offp, cnt, elist, nullptr, nullptr,
            nW1b, nW2b, vW1b, biasblk, d_out, N, N * 128, N * 131,
            1.0f / (float)(N - 1), flag);
    } else {
        hipMemsetAsync((void*)(ws + oCnt), 0, (size_t)N * 4 + (size_t)N * 16 + (size_t)N * 512,
                       stream);
        count_kernel<<<(E + 255) / 256, 256, 0, stream>>>(erow, cnt, E);

        edge_kernel<true><<<(E + 127) / 128, 256, 0, stream>>>(
            hb, xf, eaf, erow, ecol, W1t, W2t, cW1t, iW1t, biasblk,
            nullptr, nullptr, fb_mi, fb_agg, E);

        node_kernel<false><<<(N + 7) / 8, 512, 0, stream>>>(
            hb, xf, v_init, nullptr, nullptr, nullptr, cnt, nullptr, fb_mi, fb_agg,
            nW1b, nW2b, vW1b, biasblk, d_out, N, N * 128, N * 131,
            1.0f / (float)(N - 1), flag);
    }
}

// Round 8
// 1674.732 us; speedup vs baseline: 2.8639x; 1.0203x over previous
//
#include <hip/hip_runtime.h>
#include <hip/hip_bf16.h>

typedef __attribute__((ext_vector_type(8))) short short8;
typedef __attribute__((ext_vector_type(4))) float f32x4;
typedef __hip_bfloat16 bf16;

__device__ __forceinline__ short f2bs_rn(float f) {   // fast RNE bf16 pack
    unsigned u = __builtin_bit_cast(unsigned, f);
    u += 0x7FFF + ((u >> 16) & 1);
    return (short)(u >> 16);
}
__device__ __forceinline__ float bs2f(short s) {
    unsigned u = ((unsigned)(unsigned short)s) << 16;
    return __builtin_bit_cast(float, u);
}
__device__ __forceinline__ float ldf(const void* p, int i, int flag) {
    return flag ? bs2f(((const short*)p)[i]) : ((const float*)p)[i];
}
__device__ __forceinline__ short ldbits(const void* p, int i, int flag) {
    return flag ? ((const short*)p)[i] : f2bs_rn(((const float*)p)[i]);
}
__device__ __forceinline__ void stf(void* p, int i, float v, int flag) {
    if (flag) ((bf16*)p)[i] = __float2bfloat16(v);
    else ((float*)p)[i] = v;
}
__device__ __forceinline__ float nz(float v) { return (v == v) ? v : 0.f; }
__device__ __forceinline__ float siluf(float v) {
    return v * __builtin_amdgcn_rcpf(1.f + __expf(-v));
}
__device__ __forceinline__ float sigmf(float v) {
    return __builtin_amdgcn_rcpf(1.f + __expf(-v));
}

// ---------------------------------------------------------------------------
__global__ void detect_kernel(const unsigned int* __restrict__ hw, int* __restrict__ flag) {
    unsigned int w = hw[threadIdx.x];
    unsigned int e = (w >> 7) & 0xFF;
    bool ok = (e >= 113 && e <= 135);
    unsigned long long m = __ballot(ok);
    if (threadIdx.x == 0) *flag = (__popcll(m) >= 32) ? 1 : 0;
}

// ---------------------------------------------------------------------------
__global__ void prep_kernel(
    const void* eW1, const void* eW2, const void* cW1, const void* iW1,
    const void* eb1, const void* eb2, const void* cb1, const void* cw2,
    const void* ib1, const void* iw2, const void* ib2, const void* nb1,
    const void* nb2, const void* vb1, const void* vW2,
    const void* nW1, const void* nW2, const void* vW1,
    short* __restrict__ W1t, short* __restrict__ W2t,
    short* __restrict__ cW1t, short* __restrict__ iW1t,
    float* __restrict__ biasblk, short* __restrict__ nW1b,
    short* __restrict__ nW2b, short* __restrict__ vW1b,
    const int* __restrict__ flagp) {
    const int flag = *flagp;
    int i = blockIdx.x * 256 + threadIdx.x;
    if (i < 36864) { int n = i / 288, k = i % 288; W1t[i] = (k < 258) ? ldbits(eW1, k * 128 + n, flag) : (short)0; return; }
    i -= 36864;
    if (i < 16384) { int n = i / 128, k = i % 128; W2t[i] = ldbits(eW2, k * 128 + n, flag); return; }
    i -= 16384;
    if (i < 16384) { int n = i / 128, k = i % 128; cW1t[i] = ldbits(cW1, k * 128 + n, flag); return; }
    i -= 16384;
    if (i < 8192) { int n = i / 128, k = i % 128; iW1t[i] = ldbits(iW1, k * 64 + n, flag); return; }
    i -= 8192;
    if (i < 1156) {
        float v;
        if (i < 128) v = ldf(eb1, i, flag);
        else if (i < 256) v = ldf(eb2, i - 128, flag);
        else if (i < 384) v = ldf(cb1, i - 256, flag);
        else if (i < 512) v = ldf(cw2, i - 384, flag);
        else if (i < 576) v = ldf(ib1, i - 512, flag);
        else if (i < 640) v = ldf(iw2, i - 576, flag);
        else if (i < 644) v = (i == 640) ? ldf(ib2, 0, flag) : 0.f;
        else if (i < 772) v = ldf(nb1, i - 644, flag);
        else if (i < 900) v = ldf(nb2, i - 772, flag);
        else if (i < 1028) v = ldf(vb1, i - 900, flag);
        else v = ldf(vW2, i - 1028, flag);
        biasblk[i] = v;
        return;
    }
    i -= 1156;
    if (i < 32768) { nW1b[i] = ldbits(nW1, i, flag); return; }
    i -= 32768;
    if (i < 16384) { nW2b[i] = ldbits(nW2, i, flag); return; }
    i -= 16384;
    if (i < 16384) { vW1b[i] = ldbits(vW1, i, flag); }
}

// ---------------------------------------------------------------------------
__global__ void convh_kernel(const void* __restrict__ h, short* __restrict__ hb,
                             const int* __restrict__ flagp, int n) {
    const int flag = *flagp;
    int i = blockIdx.x * 256 + threadIdx.x;
    if (i < n) hb[i] = ldbits(h, i, flag);
}

// ---------------------------------------------------------------------------
// CSR build
// ---------------------------------------------------------------------------
__global__ void count_kernel(const int* __restrict__ erow, int* __restrict__ cnt, int E) {
    int i = blockIdx.x * 256 + threadIdx.x;
    if (i < E) atomicAdd(&cnt[erow[i]], 1);
}

__global__ __launch_bounds__(1024) void scan1_kernel(const int* __restrict__ cnt,
                                                     int* __restrict__ off,
                                                     int* __restrict__ bsum, int N) {
    __shared__ int sm[1024];
    int t = threadIdx.x, i = blockIdx.x * 1024 + t;
    int c = (i < N) ? cnt[i] : 0;
    sm[t] = c;
    __syncthreads();
    for (int d = 1; d < 1024; d <<= 1) {
        int v = (t >= d) ? sm[t - d] : 0;
        __syncthreads();
        sm[t] += v;
        __syncthreads();
    }
    if (i < N) off[i] = sm[t] - c;
    if (t == 1023) bsum[blockIdx.x] = sm[1023];
}
__global__ void scan2_kernel(const int* __restrict__ bsum, int* __restrict__ bpre, int nb) {
    if (threadIdx.x == 0) {
        int run = 0;
        for (int b = 0; b < nb; ++b) { bpre[b] = run; run += bsum[b]; }
    }
}
__global__ void scan3_kernel(int* __restrict__ off, const int* __restrict__ bpre, int N) {
    int i = blockIdx.x * 256 + threadIdx.x;
    if (i < N) off[i] += bpre[i >> 10];
}
__global__ void fill_kernel(const int* __restrict__ erow, const int* __restrict__ off,
                            int* __restrict__ cur, int* __restrict__ elist, int E) {
    int i = blockIdx.x * 256 + threadIdx.x;
    if (i < E) {
        int r = erow[i];
        int p = off[r] + atomicAdd(&cur[r], 1);
        elist[p] = i;
    }
}

// ---------------------------------------------------------------------------
// edge kernel: 4 waves x 32 edges (2 m-tiles of 16), weights staged in LDS.
// CSR=true: slots map to elist (row-sorted) and m_i is accumulated via
// in-wave segment reduction (one atomic set per distinct row per tile).
// CSR=false: direct per-edge atomics (round-7 proven fallback).
// ---------------------------------------------------------------------------
__device__ __forceinline__ void stage_w(const short* __restrict__ src, int grs, int k0,
                                        int nrows, int wk, short* __restrict__ sW, int tid) {
    const int upr = wk >> 3;
    const int units = nrows * upr;
    for (int u = tid; u < units; u += 256) {
        int n = u / upr, c = u % upr;
        *(short8*)(sW + n * 72 + c * 8) = *(const short8*)(src + n * grs + k0 + c * 8);
    }
}

template <bool CSR>
__global__ __launch_bounds__(256, 2) void edge_kernel(
    const short* __restrict__ hb, const void* __restrict__ x,
    const void* __restrict__ eattr,
    const int* __restrict__ erow, const int* __restrict__ ecol,
    const int* __restrict__ elist,
    const short* __restrict__ W1t, const short* __restrict__ W2t,
    const short* __restrict__ cW1t, const short* __restrict__ iW1t,
    const float* __restrict__ biasblk,
    float* __restrict__ m_i, float* __restrict__ agg_x, int E,
    const int* __restrict__ flagp) {
    const int flag = *flagp;
    __shared__ __align__(16) short sW[128 * 72];        // 18432 B
    __shared__ __align__(16) short tiles[8][16 * 136];  // 34816 B
    const float* b1f = biasblk;
    const float* b2f = biasblk + 128;
    const float* cb1f = biasblk + 256;
    const float* cw2f = biasblk + 384;
    const float* ib1f = biasblk + 512;
    const float* iw2f = biasblk + 576;
    const float ib2s = biasblk[640];

    const int tid = threadIdx.x;
    const int wv = tid >> 6;
    const int lane = tid & 63;
    const int n15 = lane & 15;
    const int quad = lane >> 4;
    const int wb = blockIdx.x * 128 + wv * 32;

    int row_e[2], col_e[2];
    float dist[2], attr[2];
#pragma unroll
    for (int m = 0; m < 2; ++m) {
        int slot = wb + m * 16 + n15;
        int sL = (slot < E) ? slot : (E - 1);
        int eL = CSR ? elist[sL] : sL;
        row_e[m] = erow[eL];
        col_e[m] = ecol[eL];
        float d = 0.f;
#pragma unroll
        for (int dd = 0; dd < 3; ++dd) {
            float xd = ldf(x, row_e[m] * 3 + dd, flag) - ldf(x, col_e[m] * 3 + dd, flag);
            d += xd * xd;
        }
        dist[m] = d;
        attr[m] = ldf(eattr, eL, flag);
    }

    // ---- GEMM1: ef[32 x 288] @ W1
    f32x4 acc1[2][8];
#pragma unroll
    for (int m = 0; m < 2; ++m)
#pragma unroll
        for (int nt = 0; nt < 8; ++nt) acc1[m][nt] = (f32x4){0.f, 0.f, 0.f, 0.f};

    for (int s = 0; s < 5; ++s) {
        const int k0 = s * 64;
        const int wk = (s < 4) ? 64 : 32;
        __syncthreads();
        stage_w(W1t, 288, k0, 128, wk, sW, tid);
        __syncthreads();
        const int kcs = (s < 4) ? 2 : 1;
        for (int kc2 = 0; kc2 < kcs; ++kc2) {
            const int kglob = k0 + kc2 * 32;
            short8 a[2];
#pragma unroll
            for (int m = 0; m < 2; ++m) {
                if (kglob < 128) {
                    a[m] = *(const short8*)(hb + row_e[m] * 128 + kglob + quad * 8);
                } else if (kglob < 256) {
                    a[m] = *(const short8*)(hb + col_e[m] * 128 + (kglob - 128) + quad * 8);
                } else {
#pragma unroll
                    for (int t = 0; t < 8; ++t) a[m][t] = 0;
                    if (quad == 0) { a[m][0] = f2bs_rn(dist[m]); a[m][1] = f2bs_rn(attr[m]); }
                }
            }
#pragma unroll
            for (int nt = 0; nt < 8; ++nt) {
                short8 b = *(const short8*)(sW + (nt * 16 + n15) * 72 + kc2 * 32 + quad * 8);
                acc1[0][nt] = __builtin_amdgcn_mfma_f32_16x16x32_bf16(a[0], b, acc1[0][nt], 0, 0, 0);
                acc1[1][nt] = __builtin_amdgcn_mfma_f32_16x16x32_bf16(a[1], b, acc1[1][nt], 0, 0, 0);
            }
        }
    }

    // hidden1 -> per-wave tiles
#pragma unroll
    for (int m = 0; m < 2; ++m) {
        short* tl = tiles[wv * 2 + m];
#pragma unroll
        for (int nt = 0; nt < 8; ++nt) {
            float bv = b1f[nt * 16 + n15];
#pragma unroll
            for (int r = 0; r < 4; ++r)
                tl[(quad * 4 + r) * 136 + nt * 16 + n15] = f2bs_rn(siluf(acc1[m][nt][r] + bv));
        }
    }

    // ---- GEMM2: hidden1 @ W2
    f32x4 acc2[2][8];
#pragma unroll
    for (int m = 0; m < 2; ++m)
#pragma unroll
        for (int nt = 0; nt < 8; ++nt) acc2[m][nt] = (f32x4){0.f, 0.f, 0.f, 0.f};
    for (int s = 0; s < 2; ++s) {
        __syncthreads();
        stage_w(W2t, 128, s * 64, 128, 64, sW, tid);
        __syncthreads();
        for (int kc2 = 0; kc2 < 2; ++kc2) {
            const int kc = s * 2 + kc2;
            short8 a[2];
#pragma unroll
            for (int m = 0; m < 2; ++m)
                a[m] = *(const short8*)(tiles[wv * 2 + m] + n15 * 136 + kc * 32 + quad * 8);
#pragma unroll
            for (int nt = 0; nt < 8; ++nt) {
                short8 b = *(const short8*)(sW + (nt * 16 + n15) * 72 + kc2 * 32 + quad * 8);
                acc2[0][nt] = __builtin_amdgcn_mfma_f32_16x16x32_bf16(a[0], b, acc2[0][nt], 0, 0, 0);
                acc2[1][nt] = __builtin_amdgcn_mfma_f32_16x16x32_bf16(a[1], b, acc2[1][nt], 0, 0, 0);
            }
        }
    }

    float mv[2][8][4];
#pragma unroll
    for (int m = 0; m < 2; ++m) {
        short* tl = tiles[wv * 2 + m];
#pragma unroll
        for (int nt = 0; nt < 8; ++nt) {
            float bv = b2f[nt * 16 + n15];
#pragma unroll
            for (int r = 0; r < 4; ++r) {
                float v = siluf(acc2[m][nt][r] + bv);
                mv[m][nt][r] = v;
                tl[(quad * 4 + r) * 136 + nt * 16 + n15] = f2bs_rn(v);
            }
        }
    }

    // ---- GEMM4 (inf, 64 cols) -> eij
    f32x4 acc4[2][4];
#pragma unroll
    for (int m = 0; m < 2; ++m)
#pragma unroll
        for (int nt = 0; nt < 4; ++nt) acc4[m][nt] = (f32x4){0.f, 0.f, 0.f, 0.f};
    for (int s = 0; s < 2; ++s) {
        __syncthreads();
        stage_w(iW1t, 128, s * 64, 64, 64, sW, tid);
        __syncthreads();
        for (int kc2 = 0; kc2 < 2; ++kc2) {
            const int kc = s * 2 + kc2;
            short8 a[2];
#pragma unroll
            for (int m = 0; m < 2; ++m)
                a[m] = *(const short8*)(tiles[wv * 2 + m] + n15 * 136 + kc * 32 + quad * 8);
#pragma unroll
            for (int nt = 0; nt < 4; ++nt) {
                short8 b = *(const short8*)(sW + (nt * 16 + n15) * 72 + kc2 * 32 + quad * 8);
                acc4[0][nt] = __builtin_amdgcn_mfma_f32_16x16x32_bf16(a[0], b, acc4[0][nt], 0, 0, 0);
                acc4[1][nt] = __builtin_amdgcn_mfma_f32_16x16x32_bf16(a[1], b, acc4[1][nt], 0, 0, 0);
            }
        }
    }
    float eij[2][4];
#pragma unroll
    for (int m = 0; m < 2; ++m) {
        float inp[4] = {0.f, 0.f, 0.f, 0.f};
#pragma unroll
        for (int nt = 0; nt < 4; ++nt) {
            float ib = ib1f[nt * 16 + n15];
            float iw = iw2f[nt * 16 + n15];
#pragma unroll
            for (int r = 0; r < 4; ++r) inp[r] += siluf(acc4[m][nt][r] + ib) * iw;
        }
#pragma unroll
        for (int mk = 1; mk < 16; mk <<= 1)
#pragma unroll
            for (int r = 0; r < 4; ++r) inp[r] += __shfl_xor(inp[r], mk);
#pragma unroll
        for (int r = 0; r < 4; ++r) eij[m][r] = sigmf(inp[r] + ib2s);
    }

    // ---- GEMM3 (coord) -> phi
    f32x4 acc3[2][8];
#pragma unroll
    for (int m = 0; m < 2; ++m)
#pragma unroll
        for (int nt = 0; nt < 8; ++nt) acc3[m][nt] = (f32x4){0.f, 0.f, 0.f, 0.f};
    for (int s = 0; s < 2; ++s) {
        __syncthreads();
        stage_w(cW1t, 128, s * 64, 128, 64, sW, tid);
        __syncthreads();
        for (int kc2 = 0; kc2 < 2; ++kc2) {
            const int kc = s * 2 + kc2;
            short8 a[2];
#pragma unroll
            for (int m = 0; m < 2; ++m)
                a[m] = *(const short8*)(tiles[wv * 2 + m] + n15 * 136 + kc * 32 + quad * 8);
#pragma unroll
            for (int nt = 0; nt < 8; ++nt) {
                short8 b = *(const short8*)(sW + (nt * 16 + n15) * 72 + kc2 * 32 + quad * 8);
                acc3[0][nt] = __builtin_amdgcn_mfma_f32_16x16x32_bf16(a[0], b, acc3[0][nt], 0, 0, 0);
                acc3[1][nt] = __builtin_amdgcn_mfma_f32_16x16x32_bf16(a[1], b, acc3[1][nt], 0, 0, 0);
            }
        }
    }

    // ---- epilogue + aggregation per m-tile
#pragma unroll
    for (int m = 0; m < 2; ++m) {
        float php[4] = {0.f, 0.f, 0.f, 0.f};
#pragma unroll
        for (int nt = 0; nt < 8; ++nt) {
            float cb = cb1f[nt * 16 + n15];
            float cw = cw2f[nt * 16 + n15];
#pragma unroll
            for (int r = 0; r < 4; ++r) php[r] += siluf(acc3[m][nt][r] + cb) * cw;
        }
#pragma unroll
        for (int mk = 1; mk < 16; mk <<= 1)
#pragma unroll
            for (int r = 0; r < 4; ++r) php[r] += __shfl_xor(php[r], mk);

        const int ebase = wb + m * 16;
        int er[4], ec[4];
        bool mk4[4];
#pragma unroll
        for (int r = 0; r < 4; ++r) {
            er[r] = __shfl(row_e[m], quad * 4 + r);
            ec[r] = __shfl(col_e[m], quad * 4 + r);
            mk4[r] = (ebase + quad * 4 + r) < E;
        }

        // agg_x: per-edge atomics (4 lanes: n15==0 of each quad handles its 4 edges)
        if (n15 == 0) {
#pragma unroll
            for (int r = 0; r < 4; ++r) {
                if (!mk4[r]) continue;
                float s = eij[m][r] * php[r];
#pragma unroll
                for (int d = 0; d < 3; ++d) {
                    float xd = ldf(x, er[r] * 3 + d, flag) - ldf(x, ec[r] * 3 + d, flag);
                    atomicAdd(&agg_x[er[r] * 3 + d], nz(s * xd));
                }
            }
        }

        if (CSR) {
            // m_i: in-wave segment reduction over row-sorted tile
            int p = 0;
            while (p < 16 && (ebase + p) < E) {
                int rowp = __shfl(row_e[m], p);
                unsigned bal = (unsigned)__ballot(row_e[m] == rowp) & 0xFFFFu;
                unsigned bits = (~bal) >> p;  // bit16 of ~bal is set -> bounded
                int q = p + __builtin_ctz(bits);
                float s[8];
#pragma unroll
                for (int nt = 0; nt < 8; ++nt) s[nt] = 0.f;
#pragma unroll
                for (int r = 0; r < 4; ++r) {
                    int idx = quad * 4 + r;
                    bool in = (idx >= p) && (idx < q) && ((ebase + idx) < E);
                    float w = in ? eij[m][r] : 0.f;
#pragma unroll
                    for (int nt = 0; nt < 8; ++nt) s[nt] += w * mv[m][nt][r];
                }
#pragma unroll
                for (int nt = 0; nt < 8; ++nt) {
                    s[nt] += __shfl_xor(s[nt], 16);
                    s[nt] += __shfl_xor(s[nt], 32);
                }
                if (quad == 0) {
#pragma unroll
                    for (int nt = 0; nt < 8; ++nt)
                        atomicAdd(&m_i[(size_t)rowp * 128 + nt * 16 + n15], nz(s[nt]));
                }
                p = q;
            }
        } else {
#pragma unroll
            for (int nt = 0; nt < 8; ++nt)
#pragma unroll
                for (int r = 0; r < 4; ++r)
                    if (mk4[r]) atomicAdd(&m_i[er[r] * 128 + nt * 16 + n15],
                                          nz(eij[m][r] * mv[m][nt][r]));
        }
    }
}

// ---------------------------------------------------------------------------
// node kernel: 512 thr = 4 slots x 128, reads m_i/agg_x directly.
// ---------------------------------------------------------------------------
__global__ __launch_bounds__(512) void node_kernel(
    const short* __restrict__ hb, const void* __restrict__ x,
    const void* __restrict__ v_init,
    const int* __restrict__ cnt,
    const float* __restrict__ m_i, const float* __restrict__ agg_x,
    const short* __restrict__ nW1b, const short* __restrict__ nW2b,
    const short* __restrict__ vW1b, const float* __restrict__ biasblk,
    void* __restrict__ out, int N, int xbase, int vbase, float inv_nm1,
    const int* __restrict__ flagp) {
    const int flag = *flagp;
    const float* nb1f = biasblk + 644;
    const float* nb2f = biasblk + 772;
    const float* vb1f = biasblk + 900;
    const float* vW2f = biasblk + 1028;
    __shared__ float nin[4][256];
    __shared__ float red[4][128];
    __shared__ float hid[4][128];
    const int slot = threadIdx.x >> 7;
    const int j = threadIdx.x & 127;

    for (int it = 0; it < 2; ++it) {
        const int n = blockIdx.x * 8 + it * 4 + slot;
        const bool act = (n < N);
        const int na = act ? n : (N - 1);

        nin[slot][j] = bs2f(hb[na * 128 + j]);
        nin[slot][128 + j] = nz(m_i[na * 128 + j]);
        const int c = cnt[na];
        __syncthreads();

        // vel MLP
        float vacc = vb1f[j];
#pragma unroll 8
        for (int k = 0; k < 128; ++k) vacc += nin[slot][k] * bs2f(vW1b[k * 128 + j]);
        red[slot][j] = siluf(vacc) * vW2f[j];
        __syncthreads();
        for (int s = 64; s > 0; s >>= 1) {
            if (j < s) red[slot][j] += red[slot][j + s];
            __syncthreads();
        }
        const float vscale = red[slot][0];

        // node MLP
        float acc = nb1f[j];
#pragma unroll 8
        for (int k = 0; k < 256; ++k) acc += nin[slot][k] * bs2f(nW1b[k * 128 + j]);
        hid[slot][j] = siluf(acc);
        __syncthreads();
        float o = nb2f[j];
#pragma unroll 8
        for (int k = 0; k < 128; ++k) o += hid[slot][k] * bs2f(nW2b[k * 128 + j]);
        if (act) stf(out, n * 128 + j, nz(o), flag);

        if (act && j < 3) {
            float vj = nz(ldf(v_init, n * 3 + j, flag) * vscale);
            stf(out, vbase + n * 3 + j, vj, flag);
            float xv = ldf(x, n * 3 + j, flag);
            float xo = (c > 0) ? xv + vj + nz(agg_x[n * 3 + j]) * inv_nm1 : xv;
            stf(out, xbase + n * 3 + j, nz(xo), flag);
        }
        __syncthreads();
    }
}

// ---------------------------------------------------------------------------
extern "C" void kernel_launch(void* const* d_in, const int* in_sizes, int n_in,
                              void* d_out, int out_size, void* d_ws, size_t ws_size,
                              hipStream_t stream) {
    const void* h = d_in[0];
    const void* x = d_in[1];
    const void* eattr = d_in[2];
    const void* v_init = d_in[3];
    const int* eidx = (const int*)d_in[4];

    const int N = in_sizes[0] / 128;
    const int E = in_sizes[4] / 2;
    const int* erow = eidx;
    const int* ecol = eidx + E;

    char* ws = (char*)d_ws;
    int* flag = (int*)ws;                       // 256
    short* W1t = (short*)(ws + 256);            // 73728
    short* W2t = (short*)(ws + 73984);          // 32768
    short* cW1t = (short*)(ws + 106752);        // 32768
    short* iW1t = (short*)(ws + 139520);        // 16384
    float* biasblk = (float*)(ws + 155904);     // 4624 -> pad 160768
    short* nW1b = (short*)(ws + 160768);        // 65536
    short* nW2b = (short*)(ws + 226304);        // 32768
    short* vW1b = (short*)(ws + 259072);        // 32768
    int* bsum = (int*)(ws + 291840);            // 512
    int* bpre = (int*)(ws + 292352);            // 512
    short* hb = (short*)(ws + 292864);          // N*256
    size_t o = 292864 + (size_t)N * 256;
    // zero region: cnt + cur + agg_x + m_i (contiguous)
    size_t oZero = o;
    int* cnt = (int*)(ws + o); o += (size_t)N * 4;
    int* cur = (int*)(ws + o); o += (size_t)N * 4;
    float* agg_x = (float*)(ws + o); o += (size_t)N * 12;
    float* m_i = (float*)(ws + o); o += (size_t)N * 512;
    size_t zeroBytes = o - oZero;
    // CSR extras
    int* offp = (int*)(ws + o); o += (size_t)(N + 16) * 4;
    int* elist = (int*)(ws + o); o += (size_t)E * 4;
    const size_t need_csr = o;

    const bool csr = (ws_size >= need_csr);

    detect_kernel<<<1, 64, 0, stream>>>((const unsigned int*)h, flag);

    const int prep_elems = 36864 + 16384 + 16384 + 8192 + 1156 + 32768 + 16384 + 16384;
    prep_kernel<<<(prep_elems + 255) / 256, 256, 0, stream>>>(
        d_in[5], d_in[7], d_in[9], d_in[12],
        d_in[6], d_in[8], d_in[10], d_in[11], d_in[13], d_in[14], d_in[15],
        d_in[17], d_in[19], d_in[21], d_in[22],
        d_in[16], d_in[18], d_in[20],
        W1t, W2t, cW1t, iW1t, biasblk, nW1b, nW2b, vW1b, flag);

    convh_kernel<<<(N * 128 + 255) / 256, 256, 0, stream>>>(h, hb, flag, N * 128);

    hipMemsetAsync((void*)(ws + oZero), 0, zeroBytes, stream);
    count_kernel<<<(E + 255) / 256, 256, 0, stream>>>(erow, cnt, E);

    if (csr) {
        const int nb = (N + 1023) / 1024;
        scan1_kernel<<<nb, 1024, 0, stream>>>(cnt, offp, bsum, N);
        scan2_kernel<<<1, 64, 0, stream>>>(bsum, bpre, nb);
        scan3_kernel<<<(N + 255) / 256, 256, 0, stream>>>(offp, bpre, N);
        fill_kernel<<<(E + 255) / 256, 256, 0, stream>>>(erow, offp, cur, elist, E);

        edge_kernel<true><<<(E + 127) / 128, 256, 0, stream>>>(
            hb, x, eattr, erow, ecol, elist, W1t, W2t, cW1t, iW1t, biasblk,
            m_i, agg_x, E, flag);
    } else {
        edge_kernel<false><<<(E + 127) / 128, 256, 0, stream>>>(
            hb, x, eattr, erow, ecol, nullptr, W1t, W2t, cW1t, iW1t, biasblk,
            m_i, agg_x, E, flag);
    }

    node_kernel<<<(N + 7) / 8, 512, 0, stream>>>(
        hb, x, v_init, cnt, m_i, agg_x,
        nW1b, nW2b, vW1b, biasblk, d_out, N, N * 128, N * 131,
        1.0f / (float)(N - 1), flag);
}